// Round 19
// baseline (198.928 us; speedup 1.0000x reference)
//
#include <hip/hip_runtime.h>
#include <hip/hip_bf16.h>

// Self-attention fwd, fp16 MFMA, double algebraic fusion:
//   out    = P@(x@(Wo@Wv)^T) + (Wo@bv+bo)
//   scores = (x@M@x^T)/32 + rowb|row + colb|col,  M = Wq^T@Wk
// scores + [Y|V'] on gemm256p8 (256x256, 8-phase); PV on pv128x256
// (128x256 tile, 256 blocks = 1/CU, TRIPLE-buffered BK=64, ONE sync region
// of 32 MFMA per tile, vmcnt(6)); [Gt|Bvw] merged row-routed gemm128.

typedef __attribute__((ext_vector_type(8))) _Float16 f16x8;
typedef __attribute__((ext_vector_type(4))) _Float16 f16x4;
typedef __attribute__((ext_vector_type(4))) float f32x4;

static __device__ __forceinline__ void gl_lds16(const void* g, void* s) {
  __builtin_amdgcn_global_load_lds(
      (const __attribute__((address_space(1))) void*)g,
      (__attribute__((address_space(3))) void*)s, 16, 0, 0);
}

// ------- fused prep: x cvt + Wo cvt + Wv^T/Wq^T/Wk^T + cpb -------
__global__ __launch_bounds__(256) void prep(
    const float* __restrict__ x,
    const float* __restrict__ Wq, const float* __restrict__ Wk,
    const float* __restrict__ Wo, const float* __restrict__ Wv,
    const float* __restrict__ bv, const float* __restrict__ bo,
    _Float16* __restrict__ xh, _Float16* __restrict__ Woh,
    _Float16* __restrict__ WvT, _Float16* __restrict__ WqT,
    _Float16* __restrict__ WkT, float* __restrict__ cpb) {
  const int b = blockIdx.x;
  const int tid = threadIdx.x;
  if (b < 8192) {
    const int i = b * 256 + tid;
    float4 v = reinterpret_cast<const float4*>(x)[i];
    f16x4 r = {(_Float16)v.x, (_Float16)v.y, (_Float16)v.z, (_Float16)v.w};
    reinterpret_cast<f16x4*>(xh)[i] = r;
  } else if (b < 9216) {
    const int i = (b - 8192) * 256 + tid;
    float4 v = reinterpret_cast<const float4*>(Wo)[i];
    f16x4 r = {(_Float16)v.x, (_Float16)v.y, (_Float16)v.z, (_Float16)v.w};
    reinterpret_cast<f16x4*>(Woh)[i] = r;
  } else if (b < 9984) {
    const int bb = b - 9216;
    const int which = bb >> 8;
    const float* src = which == 0 ? Wv : which == 1 ? Wq : Wk;
    _Float16* dst = which == 0 ? WvT : which == 1 ? WqT : WkT;
    __shared__ float t[64][65];
    const int tb = bb & 255;
    const int bx = (tb & 15) * 64, by = (tb >> 4) * 64;
    const int tx = tid & 63, ty = tid >> 6;
#pragma unroll
    for (int i = 0; i < 64; i += 4)
      t[ty + i][tx] = src[(long)(by + ty + i) * 1024 + bx + tx];
    __syncthreads();
#pragma unroll
    for (int i = 0; i < 64; i += 4)
      dst[(long)(bx + ty + i) * 1024 + by + tx] = (_Float16)t[tx][ty + i];
  } else {
    const int n = b - 9984;
    float s = 0.f;
    for (int d = tid; d < 1024; d += 256) s += Wo[(long)n * 1024 + d] * bv[d];
#pragma unroll
    for (int o = 32; o >= 1; o >>= 1) s += __shfl_xor(s, o);
    __shared__ float red[4];
    if ((tid & 63) == 0) red[tid >> 6] = s;
    __syncthreads();
    if (tid == 0) cpb[n] = red[0] + red[1] + red[2] + red[3] + bo[n];
  }
}

// ------- wkern: w1_d = bq·WkT[d], w2_d = bk·WqT[d], c0 = bq·bk -------
__global__ __launch_bounds__(256) void wkern(
    const float* __restrict__ bq, const float* __restrict__ bk,
    const _Float16* __restrict__ WkT, const _Float16* __restrict__ WqT,
    float* __restrict__ w1, float* __restrict__ w2, float* __restrict__ c0) {
  const int b = blockIdx.x;
  const int tid = threadIdx.x;
  float s = 0.f;
  if (b < 1024) {
    for (int e = tid; e < 1024; e += 256) s += bq[e] * (float)WkT[(long)b * 1024 + e];
  } else if (b < 2048) {
    const int d = b - 1024;
    for (int e = tid; e < 1024; e += 256) s += bk[e] * (float)WqT[(long)d * 1024 + e];
  } else {
    for (int e = tid; e < 1024; e += 256) s += bq[e] * bk[e];
  }
#pragma unroll
  for (int o = 32; o >= 1; o >>= 1) s += __shfl_xor(s, o);
  __shared__ float red[4];
  if ((tid & 63) == 0) red[tid >> 6] = s;
  __syncthreads();
  if (tid == 0) {
    const float v = red[0] + red[1] + red[2] + red[3];
    if (b < 1024) w1[b] = v;
    else if (b < 2048) w2[b - 1024] = v;
    else c0[0] = v;
  }
}

// ------- rowcol: rowb_i = (x_i·w2 + c0)/32, colb_i = (x_i·w1)/32 -------
__global__ __launch_bounds__(256) void rowcol(
    const _Float16* __restrict__ xh, const float* __restrict__ w1,
    const float* __restrict__ w2, const float* __restrict__ c0,
    float* __restrict__ rowb, float* __restrict__ colb) {
  const long i = blockIdx.x;
  const int tid = threadIdx.x;
  f16x4 xv = reinterpret_cast<const f16x4*>(xh + i * 1024)[tid];
  float4 a1 = reinterpret_cast<const float4*>(w1)[tid];
  float4 a2 = reinterpret_cast<const float4*>(w2)[tid];
  float x0 = (float)xv[0], x1 = (float)xv[1], x2 = (float)xv[2], x3 = (float)xv[3];
  float d1 = x0 * a1.x + x1 * a1.y + x2 * a1.z + x3 * a1.w;
  float d2 = x0 * a2.x + x1 * a2.y + x2 * a2.z + x3 * a2.w;
#pragma unroll
  for (int o = 32; o >= 1; o >>= 1) { d1 += __shfl_xor(d1, o); d2 += __shfl_xor(d2, o); }
  __shared__ float r1[4], r2[4];
  if ((tid & 63) == 0) { r1[tid >> 6] = d1; r2[tid >> 6] = d2; }
  __syncthreads();
  if (tid == 0) {
    colb[i] = (r1[0] + r1[1] + r1[2] + r1[3]) * 0.03125f;
    rowb[i] = (r2[0] + r2[1] + r2[2] + r2[3] + c0[0]) * 0.03125f;
  }
}

// ======================= 256x256 8-phase GEMM =======================
// EPI 2: scores -> fp16 Ch (+rowb[row]+colb[col]).
// EPI 3: [Y|V'] -> col<1024 Y; else V'^T via per-wave LDS bounce.
template <int EPI>
__global__ __launch_bounds__(512, 2) void gemm256p8(
    const _Float16* __restrict__ A, const _Float16* __restrict__ B,
    const float* __restrict__ colb, const float* __restrict__ rowb,
    _Float16* __restrict__ Ch, _Float16* __restrict__ C3,
    int M, int N, int K, long sA, long sB, long sC, float alpha) {
  __shared__ _Float16 lds[2][2][2][8192];  // [dbuf][A|B][kk][256x32 swz] 128KB

  const unsigned gx = gridDim.x, gy = gridDim.y;
  const unsigned nwg = gx * gy * gridDim.z;
  unsigned flat = (blockIdx.z * gy + blockIdx.y) * gx + blockIdx.x;
  flat = (flat & 7) * (nwg >> 3) + (flat >> 3);
  const long bz = flat / (gx * gy);
  const unsigned rem = flat % (gx * gy);
  const unsigned byi = rem % gy;   // col-major: B-strip L2-resident
  const unsigned bxi = rem / gy;

  const int tid = threadIdx.x;
  const int w = tid >> 6, lane = tid & 63;
  const int wr = w >> 2, wc = w & 3;     // 2M x 4N; per-wave 128x64
  const int lr = lane & 15, q = lane >> 4;
  const long row0 = (long)byi * 256;
  const long col0 = (long)bxi * 256;
  const int nt = K >> 6;

  const _Float16* pA = A + bz * sA;
  const _Float16* pB = B + bz * sB;

  f32x4 acc[8][4] = {};

  const int r0 = tid >> 2, c0i = ((tid & 3) - (r0 >> 1)) & 3;
  const int s1 = tid + 512;
  const int r1 = s1 >> 2, c1 = ((s1 & 3) - (r1 >> 1)) & 3;

  auto stage = [&](int t, int ab, int kk) {
    if (t >= nt) return;
    const int d = t & 1;
    const _Float16* src = ab ? pB : pA;
    const long base = ab ? col0 : row0;
    const long gk = (long)t * 64 + kk * 32;
    gl_lds16(src + (base + r0) * (long)K + gk + c0i * 8, &lds[d][ab][kk][w << 9]);
    gl_lds16(src + (base + r1) * (long)K + gk + c1 * 8,
             &lds[d][ab][kk][4096 + (w << 9)]);
  };
  auto rd = [&](int d, int ab, int kk, int r) -> f16x8 {
    const int slot = (r << 2) + ((q + (r >> 1)) & 3);
    return *(const f16x8*)&lds[d][ab][kk][slot << 3];
  };

#define PH_SYNC()                                         \
  __builtin_amdgcn_s_barrier();                           \
  asm volatile("s_waitcnt lgkmcnt(0)" ::: "memory");      \
  __builtin_amdgcn_sched_barrier(0);                      \
  __builtin_amdgcn_s_setprio(1);
#define PH_END()                                          \
  __builtin_amdgcn_s_setprio(0);                          \
  __builtin_amdgcn_sched_barrier(0);                      \
  __builtin_amdgcn_s_barrier();

  stage(0, 0, 0); stage(0, 1, 0); stage(0, 0, 1); stage(0, 1, 1);
  stage(1, 1, 0); stage(1, 0, 0); stage(1, 1, 1);
  asm volatile("s_waitcnt vmcnt(6)" ::: "memory");
  __builtin_amdgcn_s_barrier();
  __builtin_amdgcn_sched_barrier(0);

  f16x8 a[4], b[4];
  for (int t = 0; t < nt; ++t) {
    const int d = t & 1;
#pragma unroll
    for (int mi = 0; mi < 4; ++mi) a[mi] = rd(d, 0, 0, wr * 128 + mi * 16 + lr);
#pragma unroll
    for (int n = 0; n < 4; ++n) b[n] = rd(d, 1, 0, wc * 64 + n * 16 + lr);
    stage(t + 1, 0, 1);
    PH_SYNC();
#pragma unroll
    for (int mi = 0; mi < 4; ++mi)
#pragma unroll
      for (int n = 0; n < 4; ++n)
        acc[mi][n] = __builtin_amdgcn_mfma_f32_16x16x32_f16(a[mi], b[n], acc[mi][n], 0, 0, 0);
    PH_END();
#pragma unroll
    for (int mi = 0; mi < 4; ++mi) a[mi] = rd(d, 0, 0, wr * 128 + 64 + mi * 16 + lr);
    stage(t + 2, 1, 0);
    PH_SYNC();
#pragma unroll
    for (int mi = 0; mi < 4; ++mi)
#pragma unroll
      for (int n = 0; n < 4; ++n)
        acc[4 + mi][n] = __builtin_amdgcn_mfma_f32_16x16x32_f16(a[mi], b[n], acc[4 + mi][n], 0, 0, 0);
    PH_END();
#pragma unroll
    for (int mi = 0; mi < 4; ++mi) a[mi] = rd(d, 0, 1, wr * 128 + mi * 16 + lr);
#pragma unroll
    for (int n = 0; n < 4; ++n) b[n] = rd(d, 1, 1, wc * 64 + n * 16 + lr);
    stage(t + 2, 0, 0);
    PH_SYNC();
#pragma unroll
    for (int mi = 0; mi < 4; ++mi)
#pragma unroll
      for (int n = 0; n < 4; ++n)
        acc[mi][n] = __builtin_amdgcn_mfma_f32_16x16x32_f16(a[mi], b[n], acc[mi][n], 0, 0, 0);
    PH_END();
#pragma unroll
    for (int mi = 0; mi < 4; ++mi) a[mi] = rd(d, 0, 1, wr * 128 + 64 + mi * 16 + lr);
    stage(t + 2, 1, 1);
    PH_SYNC();
#pragma unroll
    for (int mi = 0; mi < 4; ++mi)
#pragma unroll
      for (int n = 0; n < 4; ++n)
        acc[4 + mi][n] = __builtin_amdgcn_mfma_f32_16x16x32_f16(a[mi], b[n], acc[4 + mi][n], 0, 0, 0);
    __builtin_amdgcn_s_setprio(0);
    __builtin_amdgcn_sched_barrier(0);
    if (t + 2 < nt) asm volatile("s_waitcnt vmcnt(6)" ::: "memory");
    else            asm volatile("s_waitcnt vmcnt(0)" ::: "memory");
    __builtin_amdgcn_s_barrier();
    __builtin_amdgcn_sched_barrier(0);
  }
#undef PH_SYNC
#undef PH_END

  if (EPI == 2) {  // scores
#pragma unroll
    for (int mi = 0; mi < 8; ++mi)
#pragma unroll
      for (int n = 0; n < 4; ++n)
#pragma unroll
        for (int r = 0; r < 4; ++r) {
          const long row = row0 + wr * 128 + mi * 16 + q * 4 + r;
          const long col = col0 + wc * 64 + n * 16 + lr;
          float v = acc[mi][n][r] * alpha;
          v += rowb[bz * 2048 + row] + colb[bz * 2048 + col];
          Ch[bz * sC + row * (long)N + col] = (_Float16)v;
        }
  } else {  // EPI 3: [Y|V']
    if (col0 < 1024) {
#pragma unroll
      for (int mi = 0; mi < 8; ++mi)
#pragma unroll
        for (int n = 0; n < 4; ++n)
#pragma unroll
          for (int r = 0; r < 4; ++r) {
            const long row = row0 + wr * 128 + mi * 16 + q * 4 + r;
            const long col = col0 + wc * 64 + n * 16 + lr;
            Ch[row * 1024 + col] = (_Float16)(acc[mi][n][r] * alpha);
          }
    } else {  // V'^T via per-wave LDS bounce
      _Float16* wb = ((_Float16*)lds) + w * 4224;  // 32 x 132 per wave
      const long b2 = row0 >> 11;
      const long s2b = (row0 & 2047) + wr * 128;
#pragma unroll
      for (int ch = 0; ch < 2; ++ch) {
#pragma unroll
        for (int nn = 0; nn < 2; ++nn) {
          const int n = ch * 2 + nn;
#pragma unroll
          for (int mi = 0; mi < 8; ++mi)
#pragma unroll
            for (int r = 0; r < 4; ++r) {
              const int cl = nn * 16 + lr;
              const int rl = mi * 16 + q * 4 + r;
              wb[cl * 132 + rl] = (_Float16)(acc[mi][n][r] * alpha);
            }
        }
        asm volatile("s_waitcnt lgkmcnt(0)" ::: "memory");
        __builtin_amdgcn_sched_barrier(0);
        const int cl = lane >> 1, sseg = (lane & 1) * 64;
        _Float16* dst = C3 +
            (b2 * 1024 + (col0 - 1024) + wc * 64 + ch * 32 + cl) * 2048 + s2b + sseg;
        const _Float16* srcp = wb + cl * 132 + sseg;
#pragma unroll
        for (int j = 0; j < 8; ++j)
          *(f16x8*)(dst + j * 8) = *(const f16x8*)(srcp + j * 8);
      }
    }
  }
}

// ======================= PV: 128x256-tile, triple-buffer BK=64 =======================
// out[row][col] = sum_s P[row][s] * Vt[b][col][s] + cpb[col];  M=8192 N=1024 K=2048.
// ONE sync region of 32 MFMA per tile; stage t+2 into buf (t+2)%3 (disjoint
// from read buf t%3 -> structurally race-free); vmcnt(6) per tile end.
__global__ __launch_bounds__(512, 1) void pv128x256(
    const _Float16* __restrict__ P, const _Float16* __restrict__ V,
    const float* __restrict__ cpb, float* __restrict__ out, int K) {
  __shared__ _Float16 lds[3][2][12288];  // [buf][kk][A 4096 | B 8192] = 144KB

  const unsigned gx = gridDim.x, gy = gridDim.y;  // 4 x 64
  const unsigned nwg = gx * gy;
  unsigned flat = blockIdx.y * gx + blockIdx.x;
  flat = (flat & 7) * (nwg >> 3) + (flat >> 3);
  const unsigned byi = flat % gy;     // row block fastest (B panel resident)
  const unsigned bxi = flat / gy;

  const int tid = threadIdx.x;
  const int w = tid >> 6, lane = tid & 63;
  const int wr = w >> 2, wc = w & 3;   // 2M x 4N; per-wave 64 x 64
  const int lr = lane & 15, q = lane >> 4;
  const long row0 = (long)byi * 128;
  const long col0 = (long)bxi * 256;
  const int nt = K >> 6;

  const _Float16* pA = P + row0 * (long)K;          // A strip [128][K]
  const _Float16* pB = V + (row0 >> 11) * 2097152L + col0 * (long)K;  // B [256][K]

  f32x4 acc[4][4] = {};

  const int rA = tid >> 2, cA = ((tid & 3) - (rA >> 1)) & 3;
  const int sB1 = tid + 512;
  const int rB1 = sB1 >> 2, cB1 = ((sB1 & 3) - (rB1 >> 1)) & 3;

  auto stage = [&](int t, int kk) {  // 3 gl_lds: 1 A + 2 B
    if (t >= nt) return;
    const int d = t % 3;
    const long gk = (long)t * 64 + kk * 32;
    gl_lds16(pA + rA * (long)K + gk + cA * 8, &lds[d][kk][w << 9]);
    gl_lds16(pB + rA * (long)K + gk + cA * 8, &lds[d][kk][4096 + (w << 9)]);
    gl_lds16(pB + rB1 * (long)K + gk + cB1 * 8, &lds[d][kk][8192 + (w << 9)]);
  };
  auto rdA = [&](int d, int kk, int r) -> f16x8 {
    const int slot = (r << 2) + ((q + (r >> 1)) & 3);
    return *(const f16x8*)&lds[d][kk][slot << 3];
  };
  auto rdB = [&](int d, int kk, int r) -> f16x8 {
    const int slot = (r << 2) + ((q + (r >> 1)) & 3);
    return *(const f16x8*)&lds[d][kk][4096 + (slot << 3)];
  };

  // prologue: tiles 0,1 fully staged (12 loads); vmcnt(6) -> tile 0 landed
  stage(0, 0); stage(0, 1); stage(1, 0); stage(1, 1);
  asm volatile("s_waitcnt vmcnt(6)" ::: "memory");
  __builtin_amdgcn_s_barrier();
  __builtin_amdgcn_sched_barrier(0);

  f16x8 a[4], b[4], a2[4], b2[4];
  for (int t = 0; t < nt; ++t) {
    const int d = t % 3;
    // read both kk halves of tile t; stage tile t+2 into buf (t+2)%3
#pragma unroll
    for (int mi = 0; mi < 4; ++mi) a[mi] = rdA(d, 0, wr * 64 + mi * 16 + lr);
#pragma unroll
    for (int n = 0; n < 4; ++n) b[n] = rdB(d, 0, wc * 64 + n * 16 + lr);
#pragma unroll
    for (int mi = 0; mi < 4; ++mi) a2[mi] = rdA(d, 1, wr * 64 + mi * 16 + lr);
#pragma unroll
    for (int n = 0; n < 4; ++n) b2[n] = rdB(d, 1, wc * 64 + n * 16 + lr);
    stage(t + 2, 0); stage(t + 2, 1);
    __builtin_amdgcn_s_barrier();
    asm volatile("s_waitcnt lgkmcnt(0)" ::: "memory");
    __builtin_amdgcn_sched_barrier(0);
    __builtin_amdgcn_s_setprio(1);
#pragma unroll
    for (int mi = 0; mi < 4; ++mi)
#pragma unroll
      for (int n = 0; n < 4; ++n)
        acc[mi][n] = __builtin_amdgcn_mfma_f32_16x16x32_f16(a[mi], b[n], acc[mi][n], 0, 0, 0);
#pragma unroll
    for (int mi = 0; mi < 4; ++mi)
#pragma unroll
      for (int n = 0; n < 4; ++n)
        acc[mi][n] = __builtin_amdgcn_mfma_f32_16x16x32_f16(a2[mi], b2[n], acc[mi][n], 0, 0, 0);
    __builtin_amdgcn_s_setprio(0);
    __builtin_amdgcn_sched_barrier(0);
    if (t + 2 < nt) asm volatile("s_waitcnt vmcnt(6)" ::: "memory");
    else            asm volatile("s_waitcnt vmcnt(0)" ::: "memory");
    __builtin_amdgcn_s_barrier();
    __builtin_amdgcn_sched_barrier(0);
  }

#pragma unroll
  for (int mi = 0; mi < 4; ++mi)
#pragma unroll
    for (int n = 0; n < 4; ++n)
#pragma unroll
      for (int r = 0; r < 4; ++r) {
        const long row = row0 + wr * 64 + mi * 16 + q * 4 + r;
        const long col = col0 + wc * 64 + n * 16 + lr;
        out[row * 1024 + col] = acc[mi][n][r] + cpb[col];
      }
}

// ======================= 128x128 GEMM (merged [Gt|Bvw]) =======================
template <int EPI, int BSH>
__global__ __launch_bounds__(256) void gemm128(
    const _Float16* __restrict__ A, const _Float16* __restrict__ B,
    const float* __restrict__ bias, float* __restrict__ Cf,
    _Float16* __restrict__ Ch,
    int M, int N, int K, long sA, long sB, long sC, float alpha, int panelW) {
  __shared__ _Float16 lds[3][2][4096];

  const unsigned gx = gridDim.x, gy = gridDim.y;
  const unsigned nwg = gx * gy * gridDim.z;
  unsigned flat = (blockIdx.z * gy + blockIdx.y) * gx + blockIdx.x;
  flat = (flat & 7) * (nwg >> 3) + (flat >> 3);
  const unsigned pb = gy * panelW;
  const long bz = flat / (gx * gy);
  const unsigned rem = flat % (gx * gy);
  const unsigned pi = rem / pb;
  const unsigned rem2 = rem % pb;
  const unsigned byi = rem2 / panelW;
  const unsigned bxi = pi * panelW + rem2 % panelW;

  const int tid = threadIdx.x;
  const int w = tid >> 6, lane = tid & 63;
  const int wr = w >> 1, wc = w & 1;
  const int lr = lane & 15, q = lane >> 4;
  const long row0 = (long)byi * 128;
  const long col0 = (long)bxi * 128;
  const int nt = K >> 5;

  const _Float16* pA = A + bz * sA;
  const _Float16* pB = BSH ? (B + (row0 >> BSH) * sB) : (B + bz * sB);

  f32x4 acc[4][4] = {};

  const int r0 = tid >> 2, c0i = ((tid & 3) - (r0 >> 1)) & 3;
  const int s1 = tid + 256;
  const int r1 = s1 >> 2, c1 = ((s1 & 3) - (r1 >> 1)) & 3;

  auto stage = [&](int kt) {
    if (kt >= nt) return;
    const int bf = kt % 3;
    const long gk = (long)kt * 32;
#pragma unroll
    for (int ab = 0; ab < 2; ++ab) {
      const _Float16* src = ab ? pB : pA;
      const long base = ab ? col0 : row0;
      gl_lds16(src + (base + r0) * (long)K + gk + c0i * 8, &lds[bf][ab][w << 9]);
      gl_lds16(src + (base + r1) * (long)K + gk + c1 * 8, &lds[bf][ab][2048 + (w << 9)]);
    }
  };
  auto rd = [&](int bf, int ab, int r) -> f16x8 {
    const int slot = (r << 2) + ((q + (r >> 1)) & 3);
    return *(const f16x8*)&lds[bf][ab][slot << 3];
  };

  stage(0); stage(1);
  asm volatile("s_waitcnt vmcnt(4)" ::: "memory");
  __builtin_amdgcn_s_barrier();
  __builtin_amdgcn_sched_barrier(0);

  for (int kt = 0; kt < nt; ++kt) {
    const int bf = kt % 3;
    stage(kt + 2);
    f16x8 a[4], b[4];
#pragma unroll
    for (int m = 0; m < 4; ++m) a[m] = rd(bf, 0, wr * 64 + m * 16 + lr);
#pragma unroll
    for (int n = 0; n < 4; ++n) b[n] = rd(bf, 1, wc * 64 + n * 16 + lr);
#pragma unroll
    for (int m = 0; m < 4; ++m)
#pragma unroll
      for (int n = 0; n < 4; ++n)
        acc[m][n] = __builtin_amdgcn_mfma_f32_16x16x32_f16(a[m], b[n], acc[m][n], 0, 0, 0);
    if (kt < nt - 2) asm volatile("s_waitcnt vmcnt(4)" ::: "memory");
    else             asm volatile("s_waitcnt vmcnt(0)" ::: "memory");
    __builtin_amdgcn_s_barrier();
    __builtin_amdgcn_sched_barrier(0);
  }

#pragma unroll
  for (int m = 0; m < 4; ++m)
#pragma unroll
    for (int n = 0; n < 4; ++n)
#pragma unroll
      for (int r = 0; r < 4; ++r) {
        const long row = row0 + wr * 64 + m * 16 + q * 4 + r;
        const long col = col0 + wc * 64 + n * 16 + lr;
        float v = acc[m][n][r] * alpha;
        if (bias) v += bias[col];
        if (EPI == 0) Cf[bz * sC + row * (long)N + col] = v;
        else          Ch[bz * sC + row * (long)N + col] = (_Float16)v;
      }
}

// ------- row softmax: read fp16 scores, write fp32 probs + fp16 in place -------
__global__ __launch_bounds__(256) void softmax16(
    _Float16* __restrict__ Ph, float* __restrict__ attn) {
  const long row = blockIdx.x;
  _Float16* ph = Ph + row * 2048;
  float* ap = attn + row * 2048;
  const int tid = threadIdx.x;
  f16x8 v = reinterpret_cast<const f16x8*>(ph)[tid];
  float x[8];
#pragma unroll
  for (int j = 0; j < 8; ++j) x[j] = (float)v[j];
  float m = x[0];
#pragma unroll
  for (int j = 1; j < 8; ++j) m = fmaxf(m, x[j]);
#pragma unroll
  for (int o = 32; o >= 1; o >>= 1) m = fmaxf(m, __shfl_xor(m, o));
  __shared__ float red[4], red2[4];
  if ((tid & 63) == 0) red[tid >> 6] = m;
  __syncthreads();
  m = fmaxf(fmaxf(red[0], red[1]), fmaxf(red[2], red[3]));
  float s = 0.f;
#pragma unroll
  for (int j = 0; j < 8; ++j) { x[j] = expf(x[j] - m); s += x[j]; }
#pragma unroll
  for (int o = 32; o >= 1; o >>= 1) s += __shfl_xor(s, o);
  if ((tid & 63) == 0) red2[tid >> 6] = s;
  __syncthreads();
  s = red2[0] + red2[1] + red2[2] + red2[3];
  const float inv = 1.0f / s;
#pragma unroll
  for (int j = 0; j < 8; ++j) x[j] *= inv;
  reinterpret_cast<float4*>(ap)[tid * 2] = make_float4(x[0], x[1], x[2], x[3]);
  reinterpret_cast<float4*>(ap)[tid * 2 + 1] = make_float4(x[4], x[5], x[6], x[7]);
  f16x8 pv;
#pragma unroll
  for (int j = 0; j < 8; ++j) pv[j] = (_Float16)x[j];
  reinterpret_cast<f16x8*>(ph)[tid] = pv;
}

extern "C" void kernel_launch(void* const* d_in, const int* in_sizes, int n_in,
                              void* d_out, int out_size, void* d_ws, size_t ws_size,
                              hipStream_t stream) {
  const float* x  = (const float*)d_in[0];
  const float* Wk = (const float*)d_in[1];
  const float* bk = (const float*)d_in[2];
  const float* Wq = (const float*)d_in[3];
  const float* bq = (const float*)d_in[4];
  const float* Wv = (const float*)d_in[5];
  const float* bv = (const float*)d_in[6];
  const float* Wo = (const float*)d_in[7];
  const float* bo = (const float*)d_in[8];

  float* out  = (float*)d_out;                  // [4,2048,1024]
  float* attn = (float*)d_out + 8388608;        // [4,2048,2048]

  const size_t MB = 1024 * 1024;
  unsigned char* ws = (unsigned char*)d_ws;
  _Float16* xh   = (_Float16*)(ws + 0 * MB);    // [8192][1024]        16 MB
  _Float16* Wf   = (_Float16*)(ws + 16 * MB);   // [Gt|Bvw] [2048][1024] 4 MB
  _Float16* WkT  = (_Float16*)(ws + 20 * MB);   // A-merged: [WkT|Woh]
  _Float16* Woh  = (_Float16*)(ws + 22 * MB);
  _Float16* WqT  = (_Float16*)(ws + 24 * MB);   // B-merged: [WqT|WvT]
  _Float16* WvT  = (_Float16*)(ws + 26 * MB);
  float*    rowb = (float*)   (ws + 28 * MB);            // [8192]
  float*    colb = (float*)   (ws + 28 * MB + 32768);    // [8192]
  float*    cpb  = (float*)   (ws + 28 * MB + 65536);    // [1024]
  float*    w1   = (float*)   (ws + 28 * MB + 69632);    // [1024]
  float*    w2   = (float*)   (ws + 28 * MB + 73728);    // [1024]
  float*    c0s  = (float*)   (ws + 28 * MB + 77824);    // [1]
  _Float16* Y    = (_Float16*)(ws + 29 * MB);   // [8192][1024]        16 MB
  _Float16* Vt   = (_Float16*)(ws + 45 * MB);   // V'^T [4][1024][2048] 16 MB
  _Float16* Ph   = (_Float16*)(ws + 61 * MB);   // [4][2048][2048]     32 MB

  dim3 blk(256);
  dim3 blk5(512);
  const _Float16* nullh = nullptr;

  hipLaunchKernelGGL(prep, dim3(11008), blk, 0, stream,
                     x, Wq, Wk, Wo, Wv, bv, bo, xh, Woh, WvT, WqT, WkT, cpb);
  hipLaunchKernelGGL(wkern, dim3(2049), blk, 0, stream, bq, bk, WkT, WqT, w1, w2, c0s);
  // [Gt|Bvw] merged: A=[WkT;Woh] (contig), B row-routed [WqT;WvT]
  hipLaunchKernelGGL((gemm128<1, 10>), dim3(8, 16, 1), blk, 0, stream,
                     WkT, WqT, (const float*)nullptr, (float*)nullptr, Wf,
                     2048, 1024, 1024, 0L, 1048576L, 0L, 1.0f, 8);
  hipLaunchKernelGGL(rowcol, dim3(8192), blk, 0, stream, xh, w1, w2, c0s, rowb, colb);
  // [Y|V'] = x @ [Gt|Bvw]^T   (8-phase 256²)
  hipLaunchKernelGGL((gemm256p8<3>), dim3(8, 32, 1), blk5, 0, stream,
                     xh, Wf, (const float*)nullptr, (const float*)nullptr, Y, Vt,
                     8192, 2048, 1024, 0L, 0L, 0L, 1.0f);
  // scores (fp16) = Y@x^T/32 + rowb + colb   (8-phase 256², batched)
  hipLaunchKernelGGL((gemm256p8<2>), dim3(8, 8, 4), blk5, 0, stream,
                     Y, xh, colb, rowb, Ph, (_Float16*)nullh,
                     2048, 2048, 1024, 2097152L, 2097152L, 4194304L, 0.03125f);
  hipLaunchKernelGGL(softmax16, dim3(8192), blk, 0, stream, Ph, attn);
  // out = P @ V' + cpb   (128x256 triple-buffer BK=64, 1 sync region/tile)
  hipLaunchKernelGGL(pv128x256, dim3(4, 64), blk5, 0, stream,
                     Ph, Vt, cpb, out, 2048);
}

// Round 20
// 196.572 us; speedup vs baseline: 1.0120x; 1.0120x over previous
//
#include <hip/hip_runtime.h>
#include <hip/hip_bf16.h>

// Self-attention fwd, fp16 MFMA, double algebraic fusion:
//   out    = P@(x@(Wo@Wv)^T) + (Wo@bv+bo)
//   scores = (x@M@x^T)/32 + rowb|row + colb|col,  M = Wq^T@Wk
// scores + [Y|V'] on gemm256p8 (256x256, 8-phase); PV on pv128x256
// (128x256 tile, 256 blocks = 1/CU, 2-phase/tile stage-after-free, vmcnt(6));
// [Gt|Bvw] merged row-routed gemm128.   [R18 configuration — best measured]

typedef __attribute__((ext_vector_type(8))) _Float16 f16x8;
typedef __attribute__((ext_vector_type(4))) _Float16 f16x4;
typedef __attribute__((ext_vector_type(4))) float f32x4;

static __device__ __forceinline__ void gl_lds16(const void* g, void* s) {
  __builtin_amdgcn_global_load_lds(
      (const __attribute__((address_space(1))) void*)g,
      (__attribute__((address_space(3))) void*)s, 16, 0, 0);
}

// ------- fused prep: x cvt + Wo cvt + Wv^T/Wq^T/Wk^T + cpb -------
__global__ __launch_bounds__(256) void prep(
    const float* __restrict__ x,
    const float* __restrict__ Wq, const float* __restrict__ Wk,
    const float* __restrict__ Wo, const float* __restrict__ Wv,
    const float* __restrict__ bv, const float* __restrict__ bo,
    _Float16* __restrict__ xh, _Float16* __restrict__ Woh,
    _Float16* __restrict__ WvT, _Float16* __restrict__ WqT,
    _Float16* __restrict__ WkT, float* __restrict__ cpb) {
  const int b = blockIdx.x;
  const int tid = threadIdx.x;
  if (b < 8192) {
    const int i = b * 256 + tid;
    float4 v = reinterpret_cast<const float4*>(x)[i];
    f16x4 r = {(_Float16)v.x, (_Float16)v.y, (_Float16)v.z, (_Float16)v.w};
    reinterpret_cast<f16x4*>(xh)[i] = r;
  } else if (b < 9216) {
    const int i = (b - 8192) * 256 + tid;
    float4 v = reinterpret_cast<const float4*>(Wo)[i];
    f16x4 r = {(_Float16)v.x, (_Float16)v.y, (_Float16)v.z, (_Float16)v.w};
    reinterpret_cast<f16x4*>(Woh)[i] = r;
  } else if (b < 9984) {
    const int bb = b - 9216;
    const int which = bb >> 8;
    const float* src = which == 0 ? Wv : which == 1 ? Wq : Wk;
    _Float16* dst = which == 0 ? WvT : which == 1 ? WqT : WkT;
    __shared__ float t[64][65];
    const int tb = bb & 255;
    const int bx = (tb & 15) * 64, by = (tb >> 4) * 64;
    const int tx = tid & 63, ty = tid >> 6;
#pragma unroll
    for (int i = 0; i < 64; i += 4)
      t[ty + i][tx] = src[(long)(by + ty + i) * 1024 + bx + tx];
    __syncthreads();
#pragma unroll
    for (int i = 0; i < 64; i += 4)
      dst[(long)(bx + ty + i) * 1024 + by + tx] = (_Float16)t[tx][ty + i];
  } else {
    const int n = b - 9984;
    float s = 0.f;
    for (int d = tid; d < 1024; d += 256) s += Wo[(long)n * 1024 + d] * bv[d];
#pragma unroll
    for (int o = 32; o >= 1; o >>= 1) s += __shfl_xor(s, o);
    __shared__ float red[4];
    if ((tid & 63) == 0) red[tid >> 6] = s;
    __syncthreads();
    if (tid == 0) cpb[n] = red[0] + red[1] + red[2] + red[3] + bo[n];
  }
}

// ------- wkern: w1_d = bq·WkT[d], w2_d = bk·WqT[d], c0 = bq·bk -------
__global__ __launch_bounds__(256) void wkern(
    const float* __restrict__ bq, const float* __restrict__ bk,
    const _Float16* __restrict__ WkT, const _Float16* __restrict__ WqT,
    float* __restrict__ w1, float* __restrict__ w2, float* __restrict__ c0) {
  const int b = blockIdx.x;
  const int tid = threadIdx.x;
  float s = 0.f;
  if (b < 1024) {
    for (int e = tid; e < 1024; e += 256) s += bq[e] * (float)WkT[(long)b * 1024 + e];
  } else if (b < 2048) {
    const int d = b - 1024;
    for (int e = tid; e < 1024; e += 256) s += bk[e] * (float)WqT[(long)d * 1024 + e];
  } else {
    for (int e = tid; e < 1024; e += 256) s += bq[e] * bk[e];
  }
#pragma unroll
  for (int o = 32; o >= 1; o >>= 1) s += __shfl_xor(s, o);
  __shared__ float red[4];
  if ((tid & 63) == 0) red[tid >> 6] = s;
  __syncthreads();
  if (tid == 0) {
    const float v = red[0] + red[1] + red[2] + red[3];
    if (b < 1024) w1[b] = v;
    else if (b < 2048) w2[b - 1024] = v;
    else c0[0] = v;
  }
}

// ------- rowcol: rowb_i = (x_i·w2 + c0)/32, colb_i = (x_i·w1)/32 -------
__global__ __launch_bounds__(256) void rowcol(
    const _Float16* __restrict__ xh, const float* __restrict__ w1,
    const float* __restrict__ w2, const float* __restrict__ c0,
    float* __restrict__ rowb, float* __restrict__ colb) {
  const long i = blockIdx.x;
  const int tid = threadIdx.x;
  f16x4 xv = reinterpret_cast<const f16x4*>(xh + i * 1024)[tid];
  float4 a1 = reinterpret_cast<const float4*>(w1)[tid];
  float4 a2 = reinterpret_cast<const float4*>(w2)[tid];
  float x0 = (float)xv[0], x1 = (float)xv[1], x2 = (float)xv[2], x3 = (float)xv[3];
  float d1 = x0 * a1.x + x1 * a1.y + x2 * a1.z + x3 * a1.w;
  float d2 = x0 * a2.x + x1 * a2.y + x2 * a2.z + x3 * a2.w;
#pragma unroll
  for (int o = 32; o >= 1; o >>= 1) { d1 += __shfl_xor(d1, o); d2 += __shfl_xor(d2, o); }
  __shared__ float r1[4], r2[4];
  if ((tid & 63) == 0) { r1[tid >> 6] = d1; r2[tid >> 6] = d2; }
  __syncthreads();
  if (tid == 0) {
    colb[i] = (r1[0] + r1[1] + r1[2] + r1[3]) * 0.03125f;
    rowb[i] = (r2[0] + r2[1] + r2[2] + r2[3] + c0[0]) * 0.03125f;
  }
}

// ======================= 256x256 8-phase GEMM =======================
// EPI 2: scores -> fp16 Ch (+rowb[row]+colb[col]).
// EPI 3: [Y|V'] -> col<1024 Y; else V'^T via per-wave LDS bounce.
template <int EPI>
__global__ __launch_bounds__(512, 2) void gemm256p8(
    const _Float16* __restrict__ A, const _Float16* __restrict__ B,
    const float* __restrict__ colb, const float* __restrict__ rowb,
    _Float16* __restrict__ Ch, _Float16* __restrict__ C3,
    int M, int N, int K, long sA, long sB, long sC, float alpha) {
  __shared__ _Float16 lds[2][2][2][8192];  // [dbuf][A|B][kk][256x32 swz] 128KB

  const unsigned gx = gridDim.x, gy = gridDim.y;
  const unsigned nwg = gx * gy * gridDim.z;
  unsigned flat = (blockIdx.z * gy + blockIdx.y) * gx + blockIdx.x;
  flat = (flat & 7) * (nwg >> 3) + (flat >> 3);
  const long bz = flat / (gx * gy);
  const unsigned rem = flat % (gx * gy);
  const unsigned byi = rem % gy;   // col-major: B-strip L2-resident
  const unsigned bxi = rem / gy;

  const int tid = threadIdx.x;
  const int w = tid >> 6, lane = tid & 63;
  const int wr = w >> 2, wc = w & 3;     // 2M x 4N; per-wave 128x64
  const int lr = lane & 15, q = lane >> 4;
  const long row0 = (long)byi * 256;
  const long col0 = (long)bxi * 256;
  const int nt = K >> 6;

  const _Float16* pA = A + bz * sA;
  const _Float16* pB = B + bz * sB;

  f32x4 acc[8][4] = {};

  const int r0 = tid >> 2, c0i = ((tid & 3) - (r0 >> 1)) & 3;
  const int s1 = tid + 512;
  const int r1 = s1 >> 2, c1 = ((s1 & 3) - (r1 >> 1)) & 3;

  auto stage = [&](int t, int ab, int kk) {
    if (t >= nt) return;
    const int d = t & 1;
    const _Float16* src = ab ? pB : pA;
    const long base = ab ? col0 : row0;
    const long gk = (long)t * 64 + kk * 32;
    gl_lds16(src + (base + r0) * (long)K + gk + c0i * 8, &lds[d][ab][kk][w << 9]);
    gl_lds16(src + (base + r1) * (long)K + gk + c1 * 8,
             &lds[d][ab][kk][4096 + (w << 9)]);
  };
  auto rd = [&](int d, int ab, int kk, int r) -> f16x8 {
    const int slot = (r << 2) + ((q + (r >> 1)) & 3);
    return *(const f16x8*)&lds[d][ab][kk][slot << 3];
  };

#define PH_SYNC()                                         \
  __builtin_amdgcn_s_barrier();                           \
  asm volatile("s_waitcnt lgkmcnt(0)" ::: "memory");      \
  __builtin_amdgcn_sched_barrier(0);                      \
  __builtin_amdgcn_s_setprio(1);
#define PH_END()                                          \
  __builtin_amdgcn_s_setprio(0);                          \
  __builtin_amdgcn_sched_barrier(0);                      \
  __builtin_amdgcn_s_barrier();

  stage(0, 0, 0); stage(0, 1, 0); stage(0, 0, 1); stage(0, 1, 1);
  stage(1, 1, 0); stage(1, 0, 0); stage(1, 1, 1);
  asm volatile("s_waitcnt vmcnt(6)" ::: "memory");
  __builtin_amdgcn_s_barrier();
  __builtin_amdgcn_sched_barrier(0);

  f16x8 a[4], b[4];
  for (int t = 0; t < nt; ++t) {
    const int d = t & 1;
#pragma unroll
    for (int mi = 0; mi < 4; ++mi) a[mi] = rd(d, 0, 0, wr * 128 + mi * 16 + lr);
#pragma unroll
    for (int n = 0; n < 4; ++n) b[n] = rd(d, 1, 0, wc * 64 + n * 16 + lr);
    stage(t + 1, 0, 1);
    PH_SYNC();
#pragma unroll
    for (int mi = 0; mi < 4; ++mi)
#pragma unroll
      for (int n = 0; n < 4; ++n)
        acc[mi][n] = __builtin_amdgcn_mfma_f32_16x16x32_f16(a[mi], b[n], acc[mi][n], 0, 0, 0);
    PH_END();
#pragma unroll
    for (int mi = 0; mi < 4; ++mi) a[mi] = rd(d, 0, 0, wr * 128 + 64 + mi * 16 + lr);
    stage(t + 2, 1, 0);
    PH_SYNC();
#pragma unroll
    for (int mi = 0; mi < 4; ++mi)
#pragma unroll
      for (int n = 0; n < 4; ++n)
        acc[4 + mi][n] = __builtin_amdgcn_mfma_f32_16x16x32_f16(a[mi], b[n], acc[4 + mi][n], 0, 0, 0);
    PH_END();
#pragma unroll
    for (int mi = 0; mi < 4; ++mi) a[mi] = rd(d, 0, 1, wr * 128 + mi * 16 + lr);
#pragma unroll
    for (int n = 0; n < 4; ++n) b[n] = rd(d, 1, 1, wc * 64 + n * 16 + lr);
    stage(t + 2, 0, 0);
    PH_SYNC();
#pragma unroll
    for (int mi = 0; mi < 4; ++mi)
#pragma unroll
      for (int n = 0; n < 4; ++n)
        acc[mi][n] = __builtin_amdgcn_mfma_f32_16x16x32_f16(a[mi], b[n], acc[mi][n], 0, 0, 0);
    PH_END();
#pragma unroll
    for (int mi = 0; mi < 4; ++mi) a[mi] = rd(d, 0, 1, wr * 128 + 64 + mi * 16 + lr);
    stage(t + 2, 1, 1);
    PH_SYNC();
#pragma unroll
    for (int mi = 0; mi < 4; ++mi)
#pragma unroll
      for (int n = 0; n < 4; ++n)
        acc[4 + mi][n] = __builtin_amdgcn_mfma_f32_16x16x32_f16(a[mi], b[n], acc[4 + mi][n], 0, 0, 0);
    __builtin_amdgcn_s_setprio(0);
    __builtin_amdgcn_sched_barrier(0);
    if (t + 2 < nt) asm volatile("s_waitcnt vmcnt(6)" ::: "memory");
    else            asm volatile("s_waitcnt vmcnt(0)" ::: "memory");
    __builtin_amdgcn_s_barrier();
    __builtin_amdgcn_sched_barrier(0);
  }
#undef PH_SYNC
#undef PH_END

  if (EPI == 2) {  // scores
#pragma unroll
    for (int mi = 0; mi < 8; ++mi)
#pragma unroll
      for (int n = 0; n < 4; ++n)
#pragma unroll
        for (int r = 0; r < 4; ++r) {
          const long row = row0 + wr * 128 + mi * 16 + q * 4 + r;
          const long col = col0 + wc * 64 + n * 16 + lr;
          float v = acc[mi][n][r] * alpha;
          v += rowb[bz * 2048 + row] + colb[bz * 2048 + col];
          Ch[bz * sC + row * (long)N + col] = (_Float16)v;
        }
  } else {  // EPI 3: [Y|V']
    if (col0 < 1024) {
#pragma unroll
      for (int mi = 0; mi < 8; ++mi)
#pragma unroll
        for (int n = 0; n < 4; ++n)
#pragma unroll
          for (int r = 0; r < 4; ++r) {
            const long row = row0 + wr * 128 + mi * 16 + q * 4 + r;
            const long col = col0 + wc * 64 + n * 16 + lr;
            Ch[row * 1024 + col] = (_Float16)(acc[mi][n][r] * alpha);
          }
    } else {  // V'^T via per-wave LDS bounce
      _Float16* wb = ((_Float16*)lds) + w * 4224;  // 32 x 132 per wave
      const long b2 = row0 >> 11;
      const long s2b = (row0 & 2047) + wr * 128;
#pragma unroll
      for (int ch = 0; ch < 2; ++ch) {
#pragma unroll
        for (int nn = 0; nn < 2; ++nn) {
          const int n = ch * 2 + nn;
#pragma unroll
          for (int mi = 0; mi < 8; ++mi)
#pragma unroll
            for (int r = 0; r < 4; ++r) {
              const int cl = nn * 16 + lr;
              const int rl = mi * 16 + q * 4 + r;
              wb[cl * 132 + rl] = (_Float16)(acc[mi][n][r] * alpha);
            }
        }
        asm volatile("s_waitcnt lgkmcnt(0)" ::: "memory");
        __builtin_amdgcn_sched_barrier(0);
        const int cl = lane >> 1, sseg = (lane & 1) * 64;
        _Float16* dst = C3 +
            (b2 * 1024 + (col0 - 1024) + wc * 64 + ch * 32 + cl) * 2048 + s2b + sseg;
        const _Float16* srcp = wb + cl * 132 + sseg;
#pragma unroll
        for (int j = 0; j < 8; ++j)
          *(f16x8*)(dst + j * 8) = *(const f16x8*)(srcp + j * 8);
      }
    }
  }
}

// ======================= PV: 128x256-tile 2-phase/tile pipelined =======================
// out[row][col] = sum_s P[row][s] * Vt[b][col][s] + cpb[col];  M=8192 N=1024 K=2048.
// Units: A=[128x32] (1 ld/thread), B=[256x32] (2 ld/thread); 3 loads/phase.
// P1: read kk0, stage kk1(t+1); P2: read kk1, stage kk0(t+2); vmcnt(6)/phase.
__global__ __launch_bounds__(512, 1) void pv128x256(
    const _Float16* __restrict__ P, const _Float16* __restrict__ V,
    const float* __restrict__ cpb, float* __restrict__ out, int K) {
  __shared__ _Float16 lds[2][2][12288];  // [dbuf][kk][A 4096 | B 8192] = 96KB

  const unsigned gx = gridDim.x, gy = gridDim.y;  // 4 x 64
  const unsigned nwg = gx * gy;
  unsigned flat = blockIdx.y * gx + blockIdx.x;
  flat = (flat & 7) * (nwg >> 3) + (flat >> 3);
  const unsigned byi = flat % gy;     // row block fastest (B panel resident)
  const unsigned bxi = flat / gy;

  const int tid = threadIdx.x;
  const int w = tid >> 6, lane = tid & 63;
  const int wr = w >> 2, wc = w & 3;   // 2M x 4N; per-wave 64 x 64
  const int lr = lane & 15, q = lane >> 4;
  const long row0 = (long)byi * 128;
  const long col0 = (long)bxi * 256;
  const int nt = K >> 6;

  const _Float16* pA = P + row0 * (long)K;          // A strip [128][K]
  const _Float16* pB = V + (row0 >> 11) * 2097152L + col0 * (long)K;  // B [256][K]

  f32x4 acc[4][4] = {};

  // A: slot s = tid (512 slots of 128x4); B: slots tid and tid+512 (1024 of 256x4)
  const int rA = tid >> 2, cA = ((tid & 3) - (rA >> 1)) & 3;
  const int sB1 = tid + 512;
  const int rB1 = sB1 >> 2, cB1 = ((sB1 & 3) - (rB1 >> 1)) & 3;

  auto stage = [&](int t, int kk) {  // 3 gl_lds: 1 A + 2 B
    if (t >= nt) return;
    const int d = t & 1;
    const long gk = (long)t * 64 + kk * 32;
    gl_lds16(pA + rA * (long)K + gk + cA * 8, &lds[d][kk][w << 9]);
    gl_lds16(pB + rA * (long)K + gk + cA * 8, &lds[d][kk][4096 + (w << 9)]);
    gl_lds16(pB + rB1 * (long)K + gk + cB1 * 8, &lds[d][kk][8192 + (w << 9)]);
  };
  auto rdA = [&](int d, int kk, int r) -> f16x8 {
    const int slot = (r << 2) + ((q + (r >> 1)) & 3);
    return *(const f16x8*)&lds[d][kk][slot << 3];
  };
  auto rdB = [&](int d, int kk, int r) -> f16x8 {
    const int slot = (r << 2) + ((q + (r >> 1)) & 3);
    return *(const f16x8*)&lds[d][kk][4096 + (slot << 3)];
  };

#define PH_SYNC()                                         \
  __builtin_amdgcn_s_barrier();                           \
  asm volatile("s_waitcnt lgkmcnt(0)" ::: "memory");      \
  __builtin_amdgcn_sched_barrier(0);                      \
  __builtin_amdgcn_s_setprio(1);

  // prologue: kk0(0), kk1(0), kk0(1) = 9 loads; vmcnt(6) -> kk0(0) landed
  stage(0, 0); stage(0, 1); stage(1, 0);
  asm volatile("s_waitcnt vmcnt(6)" ::: "memory");
  __builtin_amdgcn_s_barrier();
  __builtin_amdgcn_sched_barrier(0);

  f16x8 a[4], b[4];
  for (int t = 0; t < nt; ++t) {
    const int d = t & 1;
    // ---- P1: read kk0; stage kk1(t+1) ----
#pragma unroll
    for (int mi = 0; mi < 4; ++mi) a[mi] = rdA(d, 0, wr * 64 + mi * 16 + lr);
#pragma unroll
    for (int n = 0; n < 4; ++n) b[n] = rdB(d, 0, wc * 64 + n * 16 + lr);
    stage(t + 1, 1);
    PH_SYNC();
#pragma unroll
    for (int mi = 0; mi < 4; ++mi)
#pragma unroll
      for (int n = 0; n < 4; ++n)
        acc[mi][n] = __builtin_amdgcn_mfma_f32_16x16x32_f16(a[mi], b[n], acc[mi][n], 0, 0, 0);
    __builtin_amdgcn_s_setprio(0);
    __builtin_amdgcn_sched_barrier(0);
    if (t + 1 < nt) asm volatile("s_waitcnt vmcnt(6)" ::: "memory");  // kk1(t) landed
    else            asm volatile("s_waitcnt vmcnt(0)" ::: "memory");
    __builtin_amdgcn_s_barrier();
    __builtin_amdgcn_sched_barrier(0);
    // ---- P2: read kk1; stage kk0(t+2) ----
#pragma unroll
    for (int mi = 0; mi < 4; ++mi) a[mi] = rdA(d, 1, wr * 64 + mi * 16 + lr);
#pragma unroll
    for (int n = 0; n < 4; ++n) b[n] = rdB(d, 1, wc * 64 + n * 16 + lr);
    stage(t + 2, 0);
    PH_SYNC();
#pragma unroll
    for (int mi = 0; mi < 4; ++mi)
#pragma unroll
      for (int n = 0; n < 4; ++n)
        acc[mi][n] = __builtin_amdgcn_mfma_f32_16x16x32_f16(a[mi], b[n], acc[mi][n], 0, 0, 0);
    __builtin_amdgcn_s_setprio(0);
    __builtin_amdgcn_sched_barrier(0);
    if (t + 2 < nt)      asm volatile("s_waitcnt vmcnt(6)" ::: "memory");  // kk0(t+1)
    else if (t + 1 < nt) asm volatile("s_waitcnt vmcnt(3)" ::: "memory");  // tail: queue short
    else                 asm volatile("s_waitcnt vmcnt(0)" ::: "memory");
    __builtin_amdgcn_s_barrier();
    __builtin_amdgcn_sched_barrier(0);
  }
#undef PH_SYNC

#pragma unroll
  for (int mi = 0; mi < 4; ++mi)
#pragma unroll
    for (int n = 0; n < 4; ++n)
#pragma unroll
      for (int r = 0; r < 4; ++r) {
        const long row = row0 + wr * 64 + mi * 16 + q * 4 + r;
        const long col = col0 + wc * 64 + n * 16 + lr;
        out[row * 1024 + col] = acc[mi][n][r] + cpb[col];
      }
}

// ======================= 128x128 GEMM (merged [Gt|Bvw]) =======================
template <int EPI, int BSH>
__global__ __launch_bounds__(256) void gemm128(
    const _Float16* __restrict__ A, const _Float16* __restrict__ B,
    const float* __restrict__ bias, float* __restrict__ Cf,
    _Float16* __restrict__ Ch,
    int M, int N, int K, long sA, long sB, long sC, float alpha, int panelW) {
  __shared__ _Float16 lds[3][2][4096];

  const unsigned gx = gridDim.x, gy = gridDim.y;
  const unsigned nwg = gx * gy * gridDim.z;
  unsigned flat = (blockIdx.z * gy + blockIdx.y) * gx + blockIdx.x;
  flat = (flat & 7) * (nwg >> 3) + (flat >> 3);
  const unsigned pb = gy * panelW;
  const long bz = flat / (gx * gy);
  const unsigned rem = flat % (gx * gy);
  const unsigned pi = rem / pb;
  const unsigned rem2 = rem % pb;
  const unsigned byi = rem2 / panelW;
  const unsigned bxi = pi * panelW + rem2 % panelW;

  const int tid = threadIdx.x;
  const int w = tid >> 6, lane = tid & 63;
  const int wr = w >> 1, wc = w & 1;
  const int lr = lane & 15, q = lane >> 4;
  const long row0 = (long)byi * 128;
  const long col0 = (long)bxi * 128;
  const int nt = K >> 5;

  const _Float16* pA = A + bz * sA;
  const _Float16* pB = BSH ? (B + (row0 >> BSH) * sB) : (B + bz * sB);

  f32x4 acc[4][4] = {};

  const int r0 = tid >> 2, c0i = ((tid & 3) - (r0 >> 1)) & 3;
  const int s1 = tid + 256;
  const int r1 = s1 >> 2, c1 = ((s1 & 3) - (r1 >> 1)) & 3;

  auto stage = [&](int kt) {
    if (kt >= nt) return;
    const int bf = kt % 3;
    const long gk = (long)kt * 32;
#pragma unroll
    for (int ab = 0; ab < 2; ++ab) {
      const _Float16* src = ab ? pB : pA;
      const long base = ab ? col0 : row0;
      gl_lds16(src + (base + r0) * (long)K + gk + c0i * 8, &lds[bf][ab][w << 9]);
      gl_lds16(src + (base + r1) * (long)K + gk + c1 * 8, &lds[bf][ab][2048 + (w << 9)]);
    }
  };
  auto rd = [&](int bf, int ab, int r) -> f16x8 {
    const int slot = (r << 2) + ((q + (r >> 1)) & 3);
    return *(const f16x8*)&lds[bf][ab][slot << 3];
  };

  stage(0); stage(1);
  asm volatile("s_waitcnt vmcnt(4)" ::: "memory");
  __builtin_amdgcn_s_barrier();
  __builtin_amdgcn_sched_barrier(0);

  for (int kt = 0; kt < nt; ++kt) {
    const int bf = kt % 3;
    stage(kt + 2);
    f16x8 a[4], b[4];
#pragma unroll
    for (int m = 0; m < 4; ++m) a[m] = rd(bf, 0, wr * 64 + m * 16 + lr);
#pragma unroll
    for (int n = 0; n < 4; ++n) b[n] = rd(bf, 1, wc * 64 + n * 16 + lr);
#pragma unroll
    for (int m = 0; m < 4; ++m)
#pragma unroll
      for (int n = 0; n < 4; ++n)
        acc[m][n] = __builtin_amdgcn_mfma_f32_16x16x32_f16(a[m], b[n], acc[m][n], 0, 0, 0);
    if (kt < nt - 2) asm volatile("s_waitcnt vmcnt(4)" ::: "memory");
    else             asm volatile("s_waitcnt vmcnt(0)" ::: "memory");
    __builtin_amdgcn_s_barrier();
    __builtin_amdgcn_sched_barrier(0);
  }

#pragma unroll
  for (int m = 0; m < 4; ++m)
#pragma unroll
    for (int n = 0; n < 4; ++n)
#pragma unroll
      for (int r = 0; r < 4; ++r) {
        const long row = row0 + wr * 64 + m * 16 + q * 4 + r;
        const long col = col0 + wc * 64 + n * 16 + lr;
        float v = acc[m][n][r] * alpha;
        if (bias) v += bias[col];
        if (EPI == 0) Cf[bz * sC + row * (long)N + col] = v;
        else          Ch[bz * sC + row * (long)N + col] = (_Float16)v;
      }
}

// ------- row softmax: read fp16 scores, write fp32 probs + fp16 in place -------
__global__ __launch_bounds__(256) void softmax16(
    _Float16* __restrict__ Ph, float* __restrict__ attn) {
  const long row = blockIdx.x;
  _Float16* ph = Ph + row * 2048;
  float* ap = attn + row * 2048;
  const int tid = threadIdx.x;
  f16x8 v = reinterpret_cast<const f16x8*>(ph)[tid];
  float x[8];
#pragma unroll
  for (int j = 0; j < 8; ++j) x[j] = (float)v[j];
  float m = x[0];
#pragma unroll
  for (int j = 1; j < 8; ++j) m = fmaxf(m, x[j]);
#pragma unroll
  for (int o = 32; o >= 1; o >>= 1) m = fmaxf(m, __shfl_xor(m, o));
  __shared__ float red[4], red2[4];
  if ((tid & 63) == 0) red[tid >> 6] = m;
  __syncthreads();
  m = fmaxf(fmaxf(red[0], red[1]), fmaxf(red[2], red[3]));
  float s = 0.f;
#pragma unroll
  for (int j = 0; j < 8; ++j) { x[j] = expf(x[j] - m); s += x[j]; }
#pragma unroll
  for (int o = 32; o >= 1; o >>= 1) s += __shfl_xor(s, o);
  if ((tid & 63) == 0) red2[tid >> 6] = s;
  __syncthreads();
  s = red2[0] + red2[1] + red2[2] + red2[3];
  const float inv = 1.0f / s;
#pragma unroll
  for (int j = 0; j < 8; ++j) x[j] *= inv;
  reinterpret_cast<float4*>(ap)[tid * 2] = make_float4(x[0], x[1], x[2], x[3]);
  reinterpret_cast<float4*>(ap)[tid * 2 + 1] = make_float4(x[4], x[5], x[6], x[7]);
  f16x8 pv;
#pragma unroll
  for (int j = 0; j < 8; ++j) pv[j] = (_Float16)x[j];
  reinterpret_cast<f16x8*>(ph)[tid] = pv;
}

extern "C" void kernel_launch(void* const* d_in, const int* in_sizes, int n_in,
                              void* d_out, int out_size, void* d_ws, size_t ws_size,
                              hipStream_t stream) {
  const float* x  = (const float*)d_in[0];
  const float* Wk = (const float*)d_in[1];
  const float* bk = (const float*)d_in[2];
  const float* Wq = (const float*)d_in[3];
  const float* bq = (const float*)d_in[4];
  const float* Wv = (const float*)d_in[5];
  const float* bv = (const float*)d_in[6];
  const float* Wo = (const float*)d_in[7];
  const float* bo = (const float*)d_in[8];

  float* out  = (float*)d_out;                  // [4,2048,1024]
  float* attn = (float*)d_out + 8388608;        // [4,2048,2048]

  const size_t MB = 1024 * 1024;
  unsigned char* ws = (unsigned char*)d_ws;
  _Float16* xh   = (_Float16*)(ws + 0 * MB);    // [8192][1024]        16 MB
  _Float16* Wf   = (_Float16*)(ws + 16 * MB);   // [Gt|Bvw] [2048][1024] 4 MB
  _Float16* WkT  = (_Float16*)(ws + 20 * MB);   // A-merged: [WkT|Woh]
  _Float16* Woh  = (_Float16*)(ws + 22 * MB);
  _Float16* WqT  = (_Float16*)(ws + 24 * MB);   // B-merged: [WqT|WvT]
  _Float16* WvT  = (_Float16*)(ws + 26 * MB);
  float*    rowb = (float*)   (ws + 28 * MB);            // [8192]
  float*    colb = (float*)   (ws + 28 * MB + 32768);    // [8192]
  float*    cpb  = (float*)   (ws + 28 * MB + 65536);    // [1024]
  float*    w1   = (float*)   (ws + 28 * MB + 69632);    // [1024]
  float*    w2   = (float*)   (ws + 28 * MB + 73728);    // [1024]
  float*    c0s  = (float*)   (ws + 28 * MB + 77824);    // [1]
  _Float16* Y    = (_Float16*)(ws + 29 * MB);   // [8192][1024]        16 MB
  _Float16* Vt   = (_Float16*)(ws + 45 * MB);   // V'^T [4][1024][2048] 16 MB
  _Float16* Ph   = (_Float16*)(ws + 61 * MB);   // [4][2048][2048]     32 MB

  dim3 blk(256);
  dim3 blk5(512);
  const _Float16* nullh = nullptr;

  hipLaunchKernelGGL(prep, dim3(11008), blk, 0, stream,
                     x, Wq, Wk, Wo, Wv, bv, bo, xh, Woh, WvT, WqT, WkT, cpb);
  hipLaunchKernelGGL(wkern, dim3(2049), blk, 0, stream, bq, bk, WkT, WqT, w1, w2, c0s);
  // [Gt|Bvw] merged: A=[WkT;Woh] (contig), B row-routed [WqT;WvT]
  hipLaunchKernelGGL((gemm128<1, 10>), dim3(8, 16, 1), blk, 0, stream,
                     WkT, WqT, (const float*)nullptr, (float*)nullptr, Wf,
                     2048, 1024, 1024, 0L, 1048576L, 0L, 1.0f, 8);
  hipLaunchKernelGGL(rowcol, dim3(8192), blk, 0, stream, xh, w1, w2, c0s, rowb, colb);
  // [Y|V'] = x @ [Gt|Bvw]^T   (8-phase 256²)
  hipLaunchKernelGGL((gemm256p8<3>), dim3(8, 32, 1), blk5, 0, stream,
                     xh, Wf, (const float*)nullptr, (const float*)nullptr, Y, Vt,
                     8192, 2048, 1024, 0L, 0L, 0L, 1.0f);
  // scores (fp16) = Y@x^T/32 + rowb + colb   (8-phase 256², batched)
  hipLaunchKernelGGL((gemm256p8<2>), dim3(8, 8, 4), blk5, 0, stream,
                     Y, xh, colb, rowb, Ph, (_Float16*)nullh,
                     2048, 2048, 1024, 2097152L, 2097152L, 4194304L, 0.03125f);
  hipLaunchKernelGGL(softmax16, dim3(8192), blk, 0, stream, Ph, attn);
  // out = P @ V' + cpb   (128x256-tile pipelined, 256 blocks = 1/CU)
  hipLaunchKernelGGL(pv128x256, dim3(4, 64), blk5, 0, stream,
                     Ph, Vt, cpb, out, 2048);
}